// Round 11
// baseline (232.934 us; speedup 1.0000x reference)
//
#include <hip/hip_runtime.h>

#define BB 2
#define NN 32768
#define EN 32768

typedef unsigned int u32;
typedef __attribute__((ext_vector_type(8)))  short bf16x8;
typedef __attribute__((ext_vector_type(2)))  float f32x2;
typedef __attribute__((ext_vector_type(16))) float f32x16;

union U4 { uint4 u; bf16x8 h; };

// Single-instruction bf16 pack (no gfx950 builtin; RNE).
__device__ __forceinline__ u32 pk2(float lo, float hi) {
    u32 r;
    asm("v_cvt_pk_bf16_f32 %0, %1, %2" : "=v"(r) : "v"(lo), "v"(hi));
    return r;
}

// lane<->lane^32 sum via permlane32_swap (VALU, no LDS latency).
__device__ __forceinline__ float xor32_sum(float x) {
    float y = x;
    asm("v_permlane32_swap_b32 %0, %1" : "+v"(x), "+v"(y));
    return x + y;
}

__device__ __forceinline__ f32x16 MF32(bf16x8 a, bf16x8 b, f32x16 c) {
    return __builtin_amdgcn_mfma_f32_32x32x16_bf16(a, b, c, 0, 0, 0);
}

// ---------------------------------------------------------------------------
// 32x32 MFMA engine. Lane (e = lane&31, h = lane>>5).
// C/D: col = e, row(r,h) = (r&3) + 8*(r>>2) + 4h.
// pi: f(t,h,j) = 16t + 4h + (j&3) + 8*(j>>2) -> layer-to-layer pure registers.
// ---------------------------------------------------------------------------
template<bool LN>
__device__ __forceinline__ void transform32(f32x16 D, bf16x8& B0, bf16x8& B1)
{
    f32x2 p0 = {D[0],D[1]},  p1 = {D[2],D[3]},  p2 = {D[4],D[5]},  p3 = {D[6],D[7]};
    f32x2 p4 = {D[8],D[9]},  p5 = {D[10],D[11]},p6 = {D[12],D[13]},p7 = {D[14],D[15]};
    const f32x2 zz = {0.f, 0.f};
    p0 = __builtin_elementwise_max(p0, zz); p1 = __builtin_elementwise_max(p1, zz);
    p2 = __builtin_elementwise_max(p2, zz); p3 = __builtin_elementwise_max(p3, zz);
    p4 = __builtin_elementwise_max(p4, zz); p5 = __builtin_elementwise_max(p5, zz);
    p6 = __builtin_elementwise_max(p6, zz); p7 = __builtin_elementwise_max(p7, zz);
    if (LN) {
        f32x2 sv = ((p0+p1)+(p2+p3)) + ((p4+p5)+(p6+p7));
        f32x2 ta = __builtin_elementwise_fma(p0,p0,
                   __builtin_elementwise_fma(p1,p1,
                   __builtin_elementwise_fma(p2,p2, p3*p3)));
        f32x2 tb = __builtin_elementwise_fma(p4,p4,
                   __builtin_elementwise_fma(p5,p5,
                   __builtin_elementwise_fma(p6,p6, p7*p7)));
        f32x2 tv = ta + tb;
        float s = xor32_sum(sv.x + sv.y);
        float t = xor32_sum(tv.x + tv.y);
        float mu  = s * (1.f/32.f);
        float var = fmaf(-mu, mu, t * (1.f/32.f));
        float rs  = rsqrtf(var + 1e-5f);
        float nt  = -mu * rs;
        f32x2 rs2 = {rs, rs}, nt2 = {nt, nt};
        p0 = __builtin_elementwise_fma(p0, rs2, nt2);
        p1 = __builtin_elementwise_fma(p1, rs2, nt2);
        p2 = __builtin_elementwise_fma(p2, rs2, nt2);
        p3 = __builtin_elementwise_fma(p3, rs2, nt2);
        p4 = __builtin_elementwise_fma(p4, rs2, nt2);
        p5 = __builtin_elementwise_fma(p5, rs2, nt2);
        p6 = __builtin_elementwise_fma(p6, rs2, nt2);
        p7 = __builtin_elementwise_fma(p7, rs2, nt2);
    }
    U4 c;
    c.u.x = pk2(p0.x,p0.y); c.u.y = pk2(p1.x,p1.y);
    c.u.z = pk2(p2.x,p2.y); c.u.w = pk2(p3.x,p3.y);
    B0 = c.h;
    c.u.x = pk2(p4.x,p4.y); c.u.y = pk2(p5.x,p5.y);
    c.u.z = pk2(p6.x,p6.y); c.u.w = pk2(p7.x,p7.y);
    B1 = c.h;
}

// Direct aligned f32x16 LDS load (WB 64B-aligned; h*16 floats = 64B).
__device__ __forceinline__ f32x16 load_biasC(const float* WB, int base, int h) {
    return *(const f32x16*)(WB + base + h*16);
}

// WL (dwords): [Bin NT*256][Bh 32*512][Bo 512]
// unroll 8 + setprio MFMA brackets. Deep pipeline: weights prefetched 3
// layers ahead, bias C-operand 2 layers ahead (only 2 waves/SIMD cover LDS
// latency - shallow prefetch leaves both waves stalled on lgkmcnt).
// Unclamped tail over-reads (l=29..31) stay inside each kernel's SL
// allocation (verified per instantiation); junk rotates out unconsumed.
template<int NT, bool LN>
__device__ __forceinline__ f32x16 mlp32(const bf16x8* bIn,
    const u32* WL, const float* WB, int lane, int h)
{
    constexpr int HB = NT*256;
    constexpr int BO = HB + 16384;
    U4 c;
    f32x16 D = load_biasC(WB, 0, h);
    #pragma unroll
    for (int t = 0; t < NT; ++t) {
        c.u = *(const uint4*)(WL + t*256 + lane*4);
        D = MF32(c.h, bIn[t], D);
    }
    c.u = *(const uint4*)(WL + HB + lane*4);         bf16x8 w0 = c.h;
    c.u = *(const uint4*)(WL + HB + 256 + lane*4);   bf16x8 w1 = c.h;
    c.u = *(const uint4*)(WL + HB + 512 + lane*4);   bf16x8 x0 = c.h;
    c.u = *(const uint4*)(WL + HB + 768 + lane*4);   bf16x8 x1 = c.h;
    c.u = *(const uint4*)(WL + HB + 1024 + lane*4);  bf16x8 y0 = c.h;
    c.u = *(const uint4*)(WL + HB + 1280 + lane*4);  bf16x8 y1 = c.h;
    f32x16 pb = load_biasC(WB, 32, h);
    f32x16 qb = load_biasC(WB, 64, h);
    bf16x8 B0, B1;
    transform32<LN>(D, B0, B1);
    #pragma unroll 8
    for (int l = 0; l < 32; ++l) {
        c.u = *(const uint4*)(WL + HB + (l+3)*512 + lane*4);       bf16x8 nw0 = c.h;
        c.u = *(const uint4*)(WL + HB + (l+3)*512 + 256 + lane*4); bf16x8 nw1 = c.h;
        f32x16 nb = load_biasC(WB, 32 + (l+2)*32, h);
        __builtin_amdgcn_s_setprio(1);
        f32x16 E = MF32(w0, B0, pb);
        E = MF32(w1, B1, E);
        __builtin_amdgcn_s_setprio(0);
        transform32<LN>(E, B0, B1);
        w0 = x0; w1 = x1; x0 = y0; x1 = y1; y0 = nw0; y1 = nw1;
        pb = qb; qb = nb;
    }
    c.u = *(const uint4*)(WL + BO + lane*4);        bf16x8 o0 = c.h;
    c.u = *(const uint4*)(WL + BO + 256 + lane*4);  bf16x8 o1 = c.h;
    f32x16 Co = load_biasC(WB, 1056, h);
    __builtin_amdgcn_s_setprio(1);
    f32x16 O = MF32(o0, B0, Co);
    O = MF32(o1, B1, O);
    __builtin_amdgcn_s_setprio(0);
    return O;
}

// ---------------------------------------------------------------------------
// Staging. DMA linear; biases permuted to the C-operand layout.
// ---------------------------------------------------------------------------
__device__ __forceinline__ void stage_dma(u32* WL, const u32* __restrict__ Wp,
                                          int wtot, int tid, int nthr)
{
    const int lane = tid & 63;
    const int step = (nthr >> 6) * 256;
    for (int C = (tid >> 6)*256; C < wtot; C += step)
        __builtin_amdgcn_global_load_lds(
            (const __attribute__((address_space(1))) u32*)(Wp + C + lane*4),
            (__attribute__((address_space(3))) u32*)(WL + C), 16, 0, 0);
}

// WB (floats): [0..32) bin | [32..1056) hidden | [1056..1088) out
__device__ __forceinline__ void stage_bias(float* WB,
    const float* __restrict__ bin, const float* __restrict__ bhid,
    const float* __restrict__ bo, int nbo, int tid, int nthr)
{
    for (int i = tid; i < 1088; i += nthr) {
        float v;
        if (i < 32) {
            int w = i, hh = w>>4, r = w&15;
            int f = (r&3) + 8*(r>>2) + 4*hh;
            v = bin[f];
        } else if (i < 1056) {
            int l = (i-32)>>5, w = (i-32)&31, hh = w>>4, r = w&15;
            int f = (r&3) + 8*(r>>2) + 4*hh;
            v = bhid[l*32 + f];
        } else {
            int w = i-1056, hh = w>>4, r = w&15;
            int f = (r&3) + 8*(r>>2) + 4*hh;
            v = (f < nbo) ? bo[f] : 0.f;
        }
        WB[i] = v;
    }
}

__device__ __forceinline__ void stage_weights32(
    u32* WL, float* WB, const u32* __restrict__ Wp,
    const float* __restrict__ bin, const float* __restrict__ bhid,
    const float* __restrict__ bo, int wtot, int nbo, int tid, int nthr)
{
    stage_dma(WL, Wp, wtot, tid, nthr);
    stage_bias(WB, bin, bhid, bo, nbo, tid, nthr);
    __syncthreads();
}

// ---------------------------------------------------------------------------
// prep: weight packing to 32x32 pi layout + LN folds + per-batch g-fold bias
// + agg zeroing (replaces the separate memset dispatch).
// ---------------------------------------------------------------------------
__device__ __forceinline__ void pack_body32(
    const float* __restrict__ Win, const float* __restrict__ Wh,
    const float* __restrict__ Wout, const float* __restrict__ lng,
    u32* __restrict__ dst, int din, int dout, int NT, int lb, int tid)
{
    int t = lb * 256 + tid;
    int binW = NT * 256;
    int tot = binW + 16384 + 512;
    if (t >= tot) return;
    float lo, hi;
    if (t < binW) {
        int tt = t>>8, rem = t&255, ln_ = rem>>2, d = rem&3;
        int hh = ln_>>5, m = ln_&31;
        int f0 = 16*tt + 4*hh + 2*(d&1) + 8*(d>>1);
        lo = (f0   < din) ? Win[f0*32 + m]     : 0.f;
        hi = (f0+1 < din) ? Win[(f0+1)*32 + m] : 0.f;
    } else if (t < binW + 16384) {
        int u = t - binW, l = u>>9, v = u&511;
        int tt = v>>8, rem = v&255, ln_ = rem>>2, d = rem&3;
        int hh = ln_>>5, m = ln_&31;
        int f0 = 16*tt + 4*hh + 2*(d&1) + 8*(d>>1);
        lo = Wh[l*1024 + f0*32 + m];
        hi = Wh[l*1024 + (f0+1)*32 + m];
        if (lng) { lo *= lng[l*32 + f0]; hi *= lng[l*32 + f0 + 1]; }
    } else {
        int u = t - binW - 16384;
        int tt = u>>8, rem = u&255, ln_ = rem>>2, d = rem&3;
        int hh = ln_>>5, m = ln_&31;
        int f0 = 16*tt + 4*hh + 2*(d&1) + 8*(d>>1);
        lo = (m < dout) ? Wout[f0*dout + m]     : 0.f;
        hi = (m < dout) ? Wout[(f0+1)*dout + m] : 0.f;
        if (lng) { lo *= lng[1024 + f0]; hi *= lng[1024 + f0 + 1]; }
    }
    dst[t] = pk2(lo, hi);
}

__device__ __forceinline__ void fold_body(
    const float* __restrict__ Wh,   const float* __restrict__ bh,
    const float* __restrict__ Wout, const float* __restrict__ bout,
    const float* __restrict__ lnb,  float* __restrict__ fb, int lb, int tid)
{
    int j = lb * 256 + tid;
    if (j < 1024) {
        int l = j >> 5, jj = j & 31;
        float acc = bh[j];
        #pragma unroll
        for (int k = 0; k < 32; ++k)
            acc = fmaf(lnb[l*32 + k], Wh[l*1024 + k*32 + jj], acc);
        fb[j] = acc;
    } else if (j < 1024 + 16) {
        int jj = j - 1024;
        float acc = bout[jj];
        #pragma unroll
        for (int k = 0; k < 32; ++k)
            acc = fmaf(lnb[1024 + k], Wout[k*16 + jj], acc);
        fb[j] = acc;
    }
}

// blocks: ne 67 | ed 67 | pe 69 | pv 68 | de 67 | fold pe 5 | fold pv 5 | g 1
//         | agg-zero 512  => 861 total
__global__ __launch_bounds__(256) void prep_kernel(
    const float* ne_Win, const float* ne_Wh, const float* ne_Wout,
    const float* ed_Win, const float* ed_Wh, const float* ed_Wout,
    const float* pe_Win, const float* pe_Wh, const float* pe_Wout,
    const float* pe_lng, const float* pe_lnb, const float* pe_bh, const float* pe_bout,
    const float* pe_bin,
    const float* pv_Win, const float* pv_Wh, const float* pv_Wout,
    const float* pv_lng, const float* pv_lnb, const float* pv_bh, const float* pv_bout,
    const float* pv_bin,
    const float* de_Win, const float* de_Wh, const float* de_Wout,
    const float* gvec,
    u32* Wne, u32* Wed, u32* Wpe, u32* Wpv, u32* Wde,
    float* Fpe, float* Fpv, float* aggZ)
{
    int bx = blockIdx.x, tid = threadIdx.x;
    if      (bx < 67)  pack_body32(ne_Win, ne_Wh, ne_Wout, nullptr, Wne,  7, 16, 1, bx,       tid);
    else if (bx < 134) pack_body32(ed_Win, ed_Wh, ed_Wout, nullptr, Wed,  5, 16, 1, bx - 67,  tid);
    else if (bx < 203) pack_body32(pe_Win, pe_Wh, pe_Wout, pe_lng,  Wpe, 48, 16, 3, bx - 134, tid);
    else if (bx < 271) pack_body32(pv_Win, pv_Wh, pv_Wout, pv_lng,  Wpv, 32, 16, 2, bx - 203, tid);
    else if (bx < 338) pack_body32(de_Win, de_Wh, de_Wout, nullptr, Wde, 16,  3, 1, bx - 271, tid);
    else if (bx < 343) fold_body(pe_Wh, pe_bh, pe_Wout, pe_bout, pe_lnb, Fpe, bx - 338, tid);
    else if (bx < 348) fold_body(pv_Wh, pv_bh, pv_Wout, pv_bout, pv_lnb, Fpv, bx - 343, tid);
    else if (bx < 349) {
        // per-batch layer-0 bias with the g-feature folded in (f32, exact):
        // pe: g is feature 48; pv: g is feature 32.
        if (tid < 64) {
            int b = tid >> 5, f = tid & 31;
            Fpe[1040 + tid] = pe_bin[f] + gvec[b] * pe_Win[48*32 + f];
        } else if (tid < 128) {
            int u = tid - 64, b = u >> 5, f = u & 31;
            Fpv[1040 + u] = pv_bin[f] + gvec[b] * pv_Win[32*32 + f];
        }
    } else {
        // zero both agg ping-pong buffers (2 x 4MB f32): 512 blocks x 4KB x4
        const float4 z = {0.f, 0.f, 0.f, 0.f};
        float4* p = (float4*)aggZ + (size_t)(bx - 349)*1024;
        #pragma unroll
        for (int k = 0; k < 4; ++k)
            p[k*256 + tid] = z;
    }
}

// f32 source chunk -> B-frag (used for agg; ve/ee are stored bf16)
__device__ __forceinline__ bf16x8 stage_chunk(const float* __restrict__ arr,
                                              size_t e, int h)
{
    const int off = h*4;
    float4 a = *(const float4*)(arr + e*16 + off);
    float4 b = *(const float4*)(arr + e*16 + off + 8);
    U4 c;
    c.u.x = pk2(a.x, a.y); c.u.y = pk2(a.z, a.w);
    c.u.z = pk2(b.x, b.y); c.u.w = pk2(b.z, b.w);
    return c.h;
}

#define WAVE_SETUP \
    const int lane = threadIdx.x & 63; \
    const int wid  = threadIdx.x >> 6; \
    const int el = lane & 31, h = lane >> 5;

// ---------------------------------------------------------------------------
// encode: 512 blocks x 512 thr, 2 blocks/CU. Outputs ve/ee as bf16
// (numerically identical to f32 store + consumer pk2).
// ---------------------------------------------------------------------------
__global__ __launch_bounds__(512, 4) void encode_kernel(
    const float* __restrict__ nodes, const float* __restrict__ edges,
    const float* __restrict__ gvec,
    const int* __restrict__ senders, const int* __restrict__ receivers,
    const u32* __restrict__ Wne, const float* __restrict__ ne_bin,
    const float* __restrict__ ne_bh, const float* __restrict__ ne_bout,
    const u32* __restrict__ Wed, const float* __restrict__ ed_bin,
    const float* __restrict__ ed_bh, const float* __restrict__ ed_bout,
    u32* __restrict__ veB, u32* __restrict__ eeB)
{
    __shared__ __align__(64) u32 SL[17152 + 1280];
    u32* WL = SL;
    float* WB = (float*)(SL + 17152);
    WAVE_SETUP
    const bool edge_stage = blockIdx.x >= 256;
    stage_weights32(WL, WB,
                    edge_stage ? Wed : Wne,
                    edge_stage ? ed_bin : ne_bin,
                    edge_stage ? ed_bh : ne_bh,
                    edge_stage ? ed_bout : ne_bout,
                    17152, 16, threadIdx.x, 512);
    const int lb = edge_stage ? (blockIdx.x - 256) : blockIdx.x;
    const int e = (lb*8 + wid)*32 + el;
    const int b = e >> 15;
    bf16x8 a0;
    {
        uint4 w; w.x = 0u; w.y = 0u; w.z = 0u; w.w = 0u;
        if (!edge_stage) {
            if (h == 0) {
                float2 v01 = *(const float2*)(nodes + (size_t)e*6);
                float2 v23 = *(const float2*)(nodes + (size_t)e*6 + 2);
                w.x = pk2(v01.x, v01.y); w.y = pk2(v23.x, v23.y);
            } else {
                float2 v45 = *(const float2*)(nodes + (size_t)e*6 + 4);
                w.x = pk2(v45.x, v45.y); w.y = pk2(gvec[b], 0.f);
            }
        } else {
            int s = senders[e], r = receivers[e];
            const float* ps = nodes + ((size_t)b*NN + s)*6;
            const float* pr = nodes + ((size_t)b*NN + r)*6;
            float2 s01 = *(const float2*)ps; float s2v = ps[2];
            float2 r01 = *(const float2*)pr; float r2v = pr[2];
            float r0 = s01.x - r01.x, r1 = s01.y - r01.y, r2 = s2v - r2v;
            if (h == 0) {
                w.x = pk2(edges[e], r0); w.y = pk2(r1, r2);
            } else {
                w.x = pk2(sqrtf(r0*r0 + r1*r1 + r2*r2), 0.f);
            }
        }
        U4 c; c.u = w; a0 = c.h;
    }
    u32* dstB = edge_stage ? eeB : veB;
    f32x16 O = mlp32<1, false>(&a0, WL, WB, lane, h);
    U4 cc;
    cc.u.x = pk2(fmaxf(O[0],0.f), fmaxf(O[1],0.f));
    cc.u.y = pk2(fmaxf(O[2],0.f), fmaxf(O[3],0.f));
    cc.u.z = pk2(fmaxf(O[4],0.f), fmaxf(O[5],0.f));
    cc.u.w = pk2(fmaxf(O[6],0.f), fmaxf(O[7],0.f));
    *(uint4*)(dstB + (size_t)e*8 + h*4) = cc.u;
}

// ---------------------------------------------------------------------------
// edge_update: 256 blocks x 512 thr, 1 block/CU. NT=3 (g folded into bias).
// bf16 in (ee, ve gathers = half the random-gather bytes); f32 atomics.
// LAST=true (step 1): ee is dead afterwards - skip the writeback.
// ---------------------------------------------------------------------------
template<bool LAST>
__global__ __launch_bounds__(512, 2) void edge_update_kernel(
    const int* __restrict__ senders, const int* __restrict__ receivers,
    const u32* __restrict__ veB, u32* __restrict__ eeB, float* __restrict__ agg,
    const u32* __restrict__ Wp, const float* __restrict__ F)
{
    __shared__ __align__(64) u32 SL[17664 + 1280 + 8*544];
    u32* WL = SL;
    float* WB = (float*)(SL + 17664);
    WAVE_SETUP
    float* X = (float*)(SL + 18944) + wid*544;
    const float* binSel = F + 1040 + ((blockIdx.x & 128) ? 32 : 0);
    stage_weights32(WL, WB, Wp, binSel, F, F + 1024, 17664, 16, threadIdx.x, 512);
    const int e0 = (blockIdx.x*8 + wid)*32;
    const int e  = e0 + el;
    const int b  = e >> 15;
    const int s  = senders[e], r_ = receivers[e];
    bf16x8 a[3];
    U4 c;
    c.u = *(const uint4*)(eeB + (size_t)e*8 + h*4);               a[0] = c.h;
    c.u = *(const uint4*)(veB + ((size_t)b*NN + s )*8 + h*4);     a[1] = c.h;
    c.u = *(const uint4*)(veB + ((size_t)b*NN + r_)*8 + h*4);     a[2] = c.h;
    f32x16 O = mlp32<3, true>(a, WL, WB, lane, h);
    float4 s1, s2;
    s1.x = fmaxf(O[0], 0.f); s1.y = fmaxf(O[1], 0.f);
    s1.z = fmaxf(O[2], 0.f); s1.w = fmaxf(O[3], 0.f);
    s2.x = fmaxf(O[4], 0.f); s2.y = fmaxf(O[5], 0.f);
    s2.z = fmaxf(O[6], 0.f); s2.w = fmaxf(O[7], 0.f);
    if (!LAST) {
        U4 cc;
        cc.u.x = pk2(s1.x, s1.y); cc.u.y = pk2(s1.z, s1.w);
        cc.u.z = pk2(s2.x, s2.y); cc.u.w = pk2(s2.z, s2.w);
        *(uint4*)(eeB + (size_t)e*8 + h*4) = cc.u;
    }
    // Transpose through wave-private LDS so each atomic instruction hits 4
    // receiver lines (16 lanes share a receiver). Atomics stay f32.
    *(float4*)(X + el*17 + h*4)     = s1;
    *(float4*)(X + el*17 + h*4 + 8) = s2;
    const int feat = lane & 15;
    #pragma unroll
    for (int rr = 0; rr < 8; ++rr) {
        int m = (lane >> 4)*8 + rr;
        float v = X[m*17 + feat];
        int rc = __shfl(r_, m);                // lane m (h=0) holds receivers
        int eg = e0 + m;
        atomicAdd(agg + ((size_t)(eg >> 15)*NN + rc)*16 + feat, v);
    }
}

// ---------------------------------------------------------------------------
// node_update: 256 blocks x 512 thr, 1 block/CU. NT=2 (g folded into bias).
// agg stays f32 (atomic target); ve is bf16. DEC: decode staged upfront with
// a SINGLE barrier (both DMA queues + both bias loops drain under one wait).
// ---------------------------------------------------------------------------
template<bool DEC>
__global__ __launch_bounds__(512, 2) void node_update_kernel(
    const float* __restrict__ agg, u32* __restrict__ veB,
    const u32* __restrict__ Wp, const float* __restrict__ F,
    const u32* __restrict__ Wde, const float* __restrict__ de_bin,
    const float* __restrict__ de_bh, const float* __restrict__ de_bout,
    float* __restrict__ out)
{
    __shared__ __align__(64) u32 SL[DEC ? (17408 + 17152 + 1280 + 1280) : (17408 + 1280)];
    u32* WL = SL;
    u32* WL2 = SL + 17408;
    float* WB  = (float*)(SL + (DEC ? 34560 : 17408));
    float* WB2 = (float*)(SL + 35840);
    WAVE_SETUP
    const float* binSel = F + 1040 + ((blockIdx.x & 128) ? 32 : 0);
    if (!DEC) {
        stage_weights32(WL, WB, Wp, binSel, F, F + 1024, 17408, 16,
                        threadIdx.x, 512);
    } else {
        stage_dma(WL,  Wp,  17408, threadIdx.x, 512);
        stage_dma(WL2, Wde, 17152, threadIdx.x, 512);
        stage_bias(WB,  binSel, F, F + 1024, 16, threadIdx.x, 512);
        stage_bias(WB2, de_bin, de_bh, de_bout, 3, threadIdx.x, 512);
        __syncthreads();
    }
    const int e = (blockIdx.x*8 + wid)*32 + el;
    bf16x8 a[2];
    a[0] = stage_chunk(agg, (size_t)e, h);
    {
        U4 c;
        c.u = *(const uint4*)(veB + (size_t)e*8 + h*4);
        a[1] = c.h;
    }
    f32x16 O = mlp32<2, true>(a, WL, WB, lane, h);
    if (!DEC) {
        U4 cc;
        cc.u.x = pk2(fmaxf(O[0],0.f), fmaxf(O[1],0.f));
        cc.u.y = pk2(fmaxf(O[2],0.f), fmaxf(O[3],0.f));
        cc.u.z = pk2(fmaxf(O[4],0.f), fmaxf(O[5],0.f));
        cc.u.w = pk2(fmaxf(O[6],0.f), fmaxf(O[7],0.f));
        *(uint4*)(veB + (size_t)e*8 + h*4) = cc.u;
    } else {
        bf16x8 D0, D1;
        transform32<false>(O, D0, D1);   // relu + pack
        f32x16 O2 = mlp32<1, false>(&D0, WL2, WB2, lane, h);
        if (h == 0) {
            out[(size_t)e*3 + 0] = fmaxf(O2[0], 0.f);
            out[(size_t)e*3 + 1] = fmaxf(O2[1], 0.f);
            out[(size_t)e*3 + 2] = fmaxf(O2[2], 0.f);
        }
    }
}

// ---------------------------------------------------------------------------
// launch
// ---------------------------------------------------------------------------
extern "C" void kernel_launch(void* const* d_in, const int* in_sizes, int n_in,
                              void* d_out, int out_size, void* d_ws, size_t ws_size,
                              hipStream_t stream)
{
    const float* nodes     = (const float*)d_in[0];
    const float* edges     = (const float*)d_in[1];
    const float* gvec      = (const float*)d_in[2];
    const int*   senders   = (const int*)  d_in[3];
    const int*   receivers = (const int*)  d_in[4];

    const float* ne_Win  = (const float*)d_in[5];
    const float* ne_bin  = (const float*)d_in[6];
    const float* ne_Wh   = (const float*)d_in[7];
    const float* ne_bh   = (const float*)d_in[8];
    const float* ne_Wout = (const float*)d_in[9];
    const float* ne_bout = (const float*)d_in[10];

    const float* ed_Win  = (const float*)d_in[11];
    const float* ed_bin  = (const float*)d_in[12];
    const float* ed_Wh   = (const float*)d_in[13];
    const float* ed_bh   = (const float*)d_in[14];
    const float* ed_Wout = (const float*)d_in[15];
    const float* ed_bout = (const float*)d_in[16];

    const float* pe_Win  = (const float*)d_in[17];
    const float* pe_bin  = (const float*)d_in[18];
    const float* pe_Wh   = (const float*)d_in[19];
    const float* pe_bh   = (const float*)d_in[20];
    const float* pe_Wout = (const float*)d_in[21];
    const float* pe_bout = (const float*)d_in[22];
    const float* pe_lng  = (const float*)d_in[23];
    const float* pe_lnb  = (const float*)d_in[24];

    const float* pv_Win  = (const float*)d_in[25];
    const float* pv_bin  = (const float*)d_in[26];
    const float* pv_Wh   = (const float*)d_in[27];
    const float* pv_bh   = (const float*)d_in[28];
    const float* pv_Wout = (const float*)d_in[29];
    const float* pv_bout = (const float*)d_in[30];
    const float* pv_lng  = (const float*)d_in[31];
    const float* pv_lnb  = (const float*)d_in[32];

    const float* de_Win  = (const float*)d_in[33];
    const float* de_bin  = (const float*)d_in[34];
    const float* de_Wh   = (const float*)d_in[35];
    const float* de_bh   = (const float*)d_in[36];
    const float* de_Wout = (const float*)d_in[37];
    const float* de_bout = (const float*)d_in[38];

    // workspace: veB | eeB (bf16, 4MB-spaced regions) | agg0 | agg1 (f32) |
    //            packed weights | folds
    float* ve   = (float*)d_ws;
    float* ee   = ve   + (size_t)1048576;
    float* agg0 = ee   + (size_t)1048576;
    float* agg1 = agg0 + (size_t)1048576;
    u32* veB = (u32*)ve;
    u32* eeB = (u32*)ee;
    u32* Wne = (u32*)(agg1 + (size_t)1048576);
    u32* Wed = Wne + 17152;
    u32* Wpe = Wed + 17152;
    u32* Wpv = Wpe + 17664;
    u32* Wde = Wpv + 17408;
    float* Fpe = (float*)(Wde + 17152);   // 1104 floats
    float* Fpv = Fpe + 1104;              // 1104 floats

    // prep also zeroes agg0/agg1 (blocks 349..860) - no separate memset
    prep_kernel<<<861, dim3(256), 0, stream>>>(
        ne_Win, ne_Wh, ne_Wout,
        ed_Win, ed_Wh, ed_Wout,
        pe_Win, pe_Wh, pe_Wout, pe_lng, pe_lnb, pe_bh, pe_bout, pe_bin,
        pv_Win, pv_Wh, pv_Wout, pv_lng, pv_lnb, pv_bh, pv_bout, pv_bin,
        de_Win, de_Wh, de_Wout, gvec,
        Wne, Wed, Wpe, Wpv, Wde, Fpe, Fpv, agg0);

    encode_kernel<<<512, dim3(512), 0, stream>>>(nodes, edges, gvec, senders, receivers,
        Wne, ne_bin, ne_bh, ne_bout,
        Wed, ed_bin, ed_bh, ed_bout, veB, eeB);

    // step 0
    edge_update_kernel<false><<<256, dim3(512), 0, stream>>>(senders, receivers,
        veB, eeB, agg0, Wpe, Fpe);
    node_update_kernel<false><<<256, dim3(512), 0, stream>>>(agg0, veB,
        Wpv, Fpv, Wde, de_bin, de_bh, de_bout, (float*)d_out);
    // step 1 (+ fused decode; ee store skipped - dead)
    edge_update_kernel<true><<<256, dim3(512), 0, stream>>>(senders, receivers,
        veB, eeB, agg1, Wpe, Fpe);
    node_update_kernel<true><<<256, dim3(512), 0, stream>>>(agg1, veB,
        Wpv, Fpv, Wde, de_bin, de_bh, de_bout, (float*)d_out);
}

// Round 12
// 232.636 us; speedup vs baseline: 1.0013x; 1.0013x over previous
//
#include <hip/hip_runtime.h>

#define BB 2
#define NN 32768
#define EN 32768

typedef unsigned int u32;
typedef __attribute__((ext_vector_type(8)))  short bf16x8;
typedef __attribute__((ext_vector_type(2)))  float f32x2;
typedef __attribute__((ext_vector_type(16))) float f32x16;

union U4 { uint4 u; bf16x8 h; };

// Single-instruction bf16 pack (no gfx950 builtin; RNE).
__device__ __forceinline__ u32 pk2(float lo, float hi) {
    u32 r;
    asm("v_cvt_pk_bf16_f32 %0, %1, %2" : "=v"(r) : "v"(lo), "v"(hi));
    return r;
}

// lane<->lane^32 sum via permlane32_swap (VALU, no LDS latency).
__device__ __forceinline__ float xor32_sum(float x) {
    float y = x;
    asm("v_permlane32_swap_b32 %0, %1" : "+v"(x), "+v"(y));
    return x + y;
}

__device__ __forceinline__ f32x16 MF32(bf16x8 a, bf16x8 b, f32x16 c) {
    return __builtin_amdgcn_mfma_f32_32x32x16_bf16(a, b, c, 0, 0, 0);
}

// ---------------------------------------------------------------------------
// 32x32 MFMA engine (round-10 champion form, frozen).
// Lane (e = lane&31, h = lane>>5).
// C/D: col = e, row(r,h) = (r&3) + 8*(r>>2) + 4h.
// pi: f(t,h,j) = 16t + 4h + (j&3) + 8*(j>>2) -> layer-to-layer pure registers.
// ---------------------------------------------------------------------------
template<bool LN>
__device__ __forceinline__ void transform32(f32x16 D, bf16x8& B0, bf16x8& B1)
{
    f32x2 p0 = {D[0],D[1]},  p1 = {D[2],D[3]},  p2 = {D[4],D[5]},  p3 = {D[6],D[7]};
    f32x2 p4 = {D[8],D[9]},  p5 = {D[10],D[11]},p6 = {D[12],D[13]},p7 = {D[14],D[15]};
    const f32x2 zz = {0.f, 0.f};
    p0 = __builtin_elementwise_max(p0, zz); p1 = __builtin_elementwise_max(p1, zz);
    p2 = __builtin_elementwise_max(p2, zz); p3 = __builtin_elementwise_max(p3, zz);
    p4 = __builtin_elementwise_max(p4, zz); p5 = __builtin_elementwise_max(p5, zz);
    p6 = __builtin_elementwise_max(p6, zz); p7 = __builtin_elementwise_max(p7, zz);
    if (LN) {
        f32x2 sv = ((p0+p1)+(p2+p3)) + ((p4+p5)+(p6+p7));
        f32x2 ta = __builtin_elementwise_fma(p0,p0,
                   __builtin_elementwise_fma(p1,p1,
                   __builtin_elementwise_fma(p2,p2, p3*p3)));
        f32x2 tb = __builtin_elementwise_fma(p4,p4,
                   __builtin_elementwise_fma(p5,p5,
                   __builtin_elementwise_fma(p6,p6, p7*p7)));
        f32x2 tv = ta + tb;
        float s = xor32_sum(sv.x + sv.y);
        float t = xor32_sum(tv.x + tv.y);
        float mu  = s * (1.f/32.f);
        float var = fmaf(-mu, mu, t * (1.f/32.f));
        float rs  = rsqrtf(var + 1e-5f);
        float nt  = -mu * rs;
        f32x2 rs2 = {rs, rs}, nt2 = {nt, nt};
        p0 = __builtin_elementwise_fma(p0, rs2, nt2);
        p1 = __builtin_elementwise_fma(p1, rs2, nt2);
        p2 = __builtin_elementwise_fma(p2, rs2, nt2);
        p3 = __builtin_elementwise_fma(p3, rs2, nt2);
        p4 = __builtin_elementwise_fma(p4, rs2, nt2);
        p5 = __builtin_elementwise_fma(p5, rs2, nt2);
        p6 = __builtin_elementwise_fma(p6, rs2, nt2);
        p7 = __builtin_elementwise_fma(p7, rs2, nt2);
    }
    U4 c;
    c.u.x = pk2(p0.x,p0.y); c.u.y = pk2(p1.x,p1.y);
    c.u.z = pk2(p2.x,p2.y); c.u.w = pk2(p3.x,p3.y);
    B0 = c.h;
    c.u.x = pk2(p4.x,p4.y); c.u.y = pk2(p5.x,p5.y);
    c.u.z = pk2(p6.x,p6.y); c.u.w = pk2(p7.x,p7.y);
    B1 = c.h;
}

// Direct aligned f32x16 LDS load (WB 64B-aligned; h*16 floats = 64B).
__device__ __forceinline__ f32x16 load_biasC(const float* WB, int base, int h) {
    return *(const f32x16*)(WB + base + h*16);
}

// WL (dwords): [Bin NT*256][Bh 32*512][Bo 512]
// unroll 8 + setprio MFMA brackets; weights depth-2, bias depth-1 (round-10
// proven; depth-3/2 regressed +4us in round 11). Prefetch clamps removed:
// l=30/31 over-reads stay inside the kernel's LDS allocation (verified per
// instantiation; passed verification rounds 8-11); junk rotates out unused.
template<int NT, bool LN>
__device__ __forceinline__ f32x16 mlp32(const bf16x8* bIn,
    const u32* WL, const float* WB, int lane, int h)
{
    constexpr int HB = NT*256;
    constexpr int BO = HB + 16384;
    U4 c;
    f32x16 D = load_biasC(WB, 0, h);
    #pragma unroll
    for (int t = 0; t < NT; ++t) {
        c.u = *(const uint4*)(WL + t*256 + lane*4);
        D = MF32(c.h, bIn[t], D);
    }
    c.u = *(const uint4*)(WL + HB + lane*4);        bf16x8 w0 = c.h;
    c.u = *(const uint4*)(WL + HB + 256 + lane*4);  bf16x8 w1 = c.h;
    c.u = *(const uint4*)(WL + HB + 512 + lane*4);  bf16x8 x0 = c.h;
    c.u = *(const uint4*)(WL + HB + 768 + lane*4);  bf16x8 x1 = c.h;
    f32x16 pb = load_biasC(WB, 32, h);
    bf16x8 B0, B1;
    transform32<LN>(D, B0, B1);
    #pragma unroll 8
    for (int l = 0; l < 32; ++l) {
        c.u = *(const uint4*)(WL + HB + (l+2)*512 + lane*4);       bf16x8 nw0 = c.h;
        c.u = *(const uint4*)(WL + HB + (l+2)*512 + 256 + lane*4); bf16x8 nw1 = c.h;
        f32x16 nb = load_biasC(WB, 32 + (l+1)*32, h);
        __builtin_amdgcn_s_setprio(1);
        f32x16 E = MF32(w0, B0, pb);
        E = MF32(w1, B1, E);
        __builtin_amdgcn_s_setprio(0);
        transform32<LN>(E, B0, B1);
        w0 = x0; w1 = x1; x0 = nw0; x1 = nw1; pb = nb;
    }
    c.u = *(const uint4*)(WL + BO + lane*4);        bf16x8 o0 = c.h;
    c.u = *(const uint4*)(WL + BO + 256 + lane*4);  bf16x8 o1 = c.h;
    f32x16 Co = load_biasC(WB, 1056, h);
    __builtin_amdgcn_s_setprio(1);
    f32x16 O = MF32(o0, B0, Co);
    O = MF32(o1, B1, O);
    __builtin_amdgcn_s_setprio(0);
    return O;
}

// ---------------------------------------------------------------------------
// Staging. DMA linear; biases permuted to the C-operand layout.
// ---------------------------------------------------------------------------
__device__ __forceinline__ void stage_dma(u32* WL, const u32* __restrict__ Wp,
                                          int wtot, int tid, int nthr)
{
    const int lane = tid & 63;
    const int step = (nthr >> 6) * 256;
    for (int C = (tid >> 6)*256; C < wtot; C += step)
        __builtin_amdgcn_global_load_lds(
            (const __attribute__((address_space(1))) u32*)(Wp + C + lane*4),
            (__attribute__((address_space(3))) u32*)(WL + C), 16, 0, 0);
}

// WB (floats): [0..32) bin | [32..1056) hidden | [1056..1088) out
__device__ __forceinline__ void stage_bias(float* WB,
    const float* __restrict__ bin, const float* __restrict__ bhid,
    const float* __restrict__ bo, int nbo, int tid, int nthr)
{
    for (int i = tid; i < 1088; i += nthr) {
        float v;
        if (i < 32) {
            int w = i, hh = w>>4, r = w&15;
            int f = (r&3) + 8*(r>>2) + 4*hh;
            v = bin[f];
        } else if (i < 1056) {
            int l = (i-32)>>5, w = (i-32)&31, hh = w>>4, r = w&15;
            int f = (r&3) + 8*(r>>2) + 4*hh;
            v = bhid[l*32 + f];
        } else {
            int w = i-1056, hh = w>>4, r = w&15;
            int f = (r&3) + 8*(r>>2) + 4*hh;
            v = (f < nbo) ? bo[f] : 0.f;
        }
        WB[i] = v;
    }
}

__device__ __forceinline__ void stage_weights32(
    u32* WL, float* WB, const u32* __restrict__ Wp,
    const float* __restrict__ bin, const float* __restrict__ bhid,
    const float* __restrict__ bo, int wtot, int nbo, int tid, int nthr)
{
    stage_dma(WL, Wp, wtot, tid, nthr);
    stage_bias(WB, bin, bhid, bo, nbo, tid, nthr);
    __syncthreads();
}

// ---------------------------------------------------------------------------
// prep: weight packing to 32x32 pi layout + LN folds + per-batch g-fold bias
// + agg zeroing (replaces the separate memset dispatch).
// ---------------------------------------------------------------------------
__device__ __forceinline__ void pack_body32(
    const float* __restrict__ Win, const float* __restrict__ Wh,
    const float* __restrict__ Wout, const float* __restrict__ lng,
    u32* __restrict__ dst, int din, int dout, int NT, int lb, int tid)
{
    int t = lb * 256 + tid;
    int binW = NT * 256;
    int tot = binW + 16384 + 512;
    if (t >= tot) return;
    float lo, hi;
    if (t < binW) {
        int tt = t>>8, rem = t&255, ln_ = rem>>2, d = rem&3;
        int hh = ln_>>5, m = ln_&31;
        int f0 = 16*tt + 4*hh + 2*(d&1) + 8*(d>>1);
        lo = (f0   < din) ? Win[f0*32 + m]     : 0.f;
        hi = (f0+1 < din) ? Win[(f0+1)*32 + m] : 0.f;
    } else if (t < binW + 16384) {
        int u = t - binW, l = u>>9, v = u&511;
        int tt = v>>8, rem = v&255, ln_ = rem>>2, d = rem&3;
        int hh = ln_>>5, m = ln_&31;
        int f0 = 16*tt + 4*hh + 2*(d&1) + 8*(d>>1);
        lo = Wh[l*1024 + f0*32 + m];
        hi = Wh[l*1024 + (f0+1)*32 + m];
        if (lng) { lo *= lng[l*32 + f0]; hi *= lng[l*32 + f0 + 1]; }
    } else {
        int u = t - binW - 16384;
        int tt = u>>8, rem = u&255, ln_ = rem>>2, d = rem&3;
        int hh = ln_>>5, m = ln_&31;
        int f0 = 16*tt + 4*hh + 2*(d&1) + 8*(d>>1);
        lo = (m < dout) ? Wout[f0*dout + m]     : 0.f;
        hi = (m < dout) ? Wout[(f0+1)*dout + m] : 0.f;
        if (lng) { lo *= lng[1024 + f0]; hi *= lng[1024 + f0 + 1]; }
    }
    dst[t] = pk2(lo, hi);
}

__device__ __forceinline__ void fold_body(
    const float* __restrict__ Wh,   const float* __restrict__ bh,
    const float* __restrict__ Wout, const float* __restrict__ bout,
    const float* __restrict__ lnb,  float* __restrict__ fb, int lb, int tid)
{
    int j = lb * 256 + tid;
    if (j < 1024) {
        int l = j >> 5, jj = j & 31;
        float acc = bh[j];
        #pragma unroll
        for (int k = 0; k < 32; ++k)
            acc = fmaf(lnb[l*32 + k], Wh[l*1024 + k*32 + jj], acc);
        fb[j] = acc;
    } else if (j < 1024 + 16) {
        int jj = j - 1024;
        float acc = bout[jj];
        #pragma unroll
        for (int k = 0; k < 32; ++k)
            acc = fmaf(lnb[1024 + k], Wout[k*16 + jj], acc);
        fb[j] = acc;
    }
}

// blocks: ne 67 | ed 67 | pe 69 | pv 68 | de 67 | fold pe 5 | fold pv 5 | g 1
//         | agg-zero 512  => 861 total
__global__ __launch_bounds__(256) void prep_kernel(
    const float* ne_Win, const float* ne_Wh, const float* ne_Wout,
    const float* ed_Win, const float* ed_Wh, const float* ed_Wout,
    const float* pe_Win, const float* pe_Wh, const float* pe_Wout,
    const float* pe_lng, const float* pe_lnb, const float* pe_bh, const float* pe_bout,
    const float* pe_bin,
    const float* pv_Win, const float* pv_Wh, const float* pv_Wout,
    const float* pv_lng, const float* pv_lnb, const float* pv_bh, const float* pv_bout,
    const float* pv_bin,
    const float* de_Win, const float* de_Wh, const float* de_Wout,
    const float* gvec,
    u32* Wne, u32* Wed, u32* Wpe, u32* Wpv, u32* Wde,
    float* Fpe, float* Fpv, float* aggZ)
{
    int bx = blockIdx.x, tid = threadIdx.x;
    if      (bx < 67)  pack_body32(ne_Win, ne_Wh, ne_Wout, nullptr, Wne,  7, 16, 1, bx,       tid);
    else if (bx < 134) pack_body32(ed_Win, ed_Wh, ed_Wout, nullptr, Wed,  5, 16, 1, bx - 67,  tid);
    else if (bx < 203) pack_body32(pe_Win, pe_Wh, pe_Wout, pe_lng,  Wpe, 48, 16, 3, bx - 134, tid);
    else if (bx < 271) pack_body32(pv_Win, pv_Wh, pv_Wout, pv_lng,  Wpv, 32, 16, 2, bx - 203, tid);
    else if (bx < 338) pack_body32(de_Win, de_Wh, de_Wout, nullptr, Wde, 16,  3, 1, bx - 271, tid);
    else if (bx < 343) fold_body(pe_Wh, pe_bh, pe_Wout, pe_bout, pe_lnb, Fpe, bx - 338, tid);
    else if (bx < 348) fold_body(pv_Wh, pv_bh, pv_Wout, pv_bout, pv_lnb, Fpv, bx - 343, tid);
    else if (bx < 349) {
        // per-batch layer-0 bias with the g-feature folded in (f32, exact):
        // pe: g is feature 48; pv: g is feature 32.
        if (tid < 64) {
            int b = tid >> 5, f = tid & 31;
            Fpe[1040 + tid] = pe_bin[f] + gvec[b] * pe_Win[48*32 + f];
        } else if (tid < 128) {
            int u = tid - 64, b = u >> 5, f = u & 31;
            Fpv[1040 + u] = pv_bin[f] + gvec[b] * pv_Win[32*32 + f];
        }
    } else {
        // zero both agg ping-pong buffers (2 x 4MB f32): 512 blocks x 4KB x4
        const float4 z = {0.f, 0.f, 0.f, 0.f};
        float4* p = (float4*)aggZ + (size_t)(bx - 349)*1024;
        #pragma unroll
        for (int k = 0; k < 4; ++k)
            p[k*256 + tid] = z;
    }
}

// f32 source chunk -> B-frag (used for agg; ve/ee are stored bf16)
__device__ __forceinline__ bf16x8 stage_chunk(const float* __restrict__ arr,
                                              size_t e, int h)
{
    const int off = h*4;
    float4 a = *(const float4*)(arr + e*16 + off);
    float4 b = *(const float4*)(arr + e*16 + off + 8);
    U4 c;
    c.u.x = pk2(a.x, a.y); c.u.y = pk2(a.z, a.w);
    c.u.z = pk2(b.x, b.y); c.u.w = pk2(b.z, b.w);
    return c.h;
}

#define WAVE_SETUP \
    const int lane = threadIdx.x & 63; \
    const int wid  = threadIdx.x >> 6; \
    const int el = lane & 31, h = lane >> 5;

// ---------------------------------------------------------------------------
// encode: 512 blocks x 512 thr, 2 blocks/CU. Outputs ve/ee as bf16
// (numerically identical to f32 store + consumer pk2).
// ---------------------------------------------------------------------------
__global__ __launch_bounds__(512, 4) void encode_kernel(
    const float* __restrict__ nodes, const float* __restrict__ edges,
    const float* __restrict__ gvec,
    const int* __restrict__ senders, const int* __restrict__ receivers,
    const u32* __restrict__ Wne, const float* __restrict__ ne_bin,
    const float* __restrict__ ne_bh, const float* __restrict__ ne_bout,
    const u32* __restrict__ Wed, const float* __restrict__ ed_bin,
    const float* __restrict__ ed_bh, const float* __restrict__ ed_bout,
    u32* __restrict__ veB, u32* __restrict__ eeB)
{
    __shared__ __align__(64) u32 SL[17152 + 1088];
    u32* WL = SL;
    float* WB = (float*)(SL + 17152);
    WAVE_SETUP
    const bool edge_stage = blockIdx.x >= 256;
    stage_weights32(WL, WB,
                    edge_stage ? Wed : Wne,
                    edge_stage ? ed_bin : ne_bin,
                    edge_stage ? ed_bh : ne_bh,
                    edge_stage ? ed_bout : ne_bout,
                    17152, 16, threadIdx.x, 512);
    const int lb = edge_stage ? (blockIdx.x - 256) : blockIdx.x;
    const int e = (lb*8 + wid)*32 + el;
    const int b = e >> 15;
    bf16x8 a0;
    {
        uint4 w; w.x = 0u; w.y = 0u; w.z = 0u; w.w = 0u;
        if (!edge_stage) {
            if (h == 0) {
                float2 v01 = *(const float2*)(nodes + (size_t)e*6);
                float2 v23 = *(const float2*)(nodes + (size_t)e*6 + 2);
                w.x = pk2(v01.x, v01.y); w.y = pk2(v23.x, v23.y);
            } else {
                float2 v45 = *(const float2*)(nodes + (size_t)e*6 + 4);
                w.x = pk2(v45.x, v45.y); w.y = pk2(gvec[b], 0.f);
            }
        } else {
            int s = senders[e], r = receivers[e];
            const float* ps = nodes + ((size_t)b*NN + s)*6;
            const float* pr = nodes + ((size_t)b*NN + r)*6;
            float2 s01 = *(const float2*)ps; float s2v = ps[2];
            float2 r01 = *(const float2*)pr; float r2v = pr[2];
            float r0 = s01.x - r01.x, r1 = s01.y - r01.y, r2 = s2v - r2v;
            if (h == 0) {
                w.x = pk2(edges[e], r0); w.y = pk2(r1, r2);
            } else {
                w.x = pk2(sqrtf(r0*r0 + r1*r1 + r2*r2), 0.f);
            }
        }
        U4 c; c.u = w; a0 = c.h;
    }
    u32* dstB = edge_stage ? eeB : veB;
    f32x16 O = mlp32<1, false>(&a0, WL, WB, lane, h);
    U4 cc;
    cc.u.x = pk2(fmaxf(O[0],0.f), fmaxf(O[1],0.f));
    cc.u.y = pk2(fmaxf(O[2],0.f), fmaxf(O[3],0.f));
    cc.u.z = pk2(fmaxf(O[4],0.f), fmaxf(O[5],0.f));
    cc.u.w = pk2(fmaxf(O[6],0.f), fmaxf(O[7],0.f));
    *(uint4*)(dstB + (size_t)e*8 + h*4) = cc.u;
}

// ---------------------------------------------------------------------------
// edge_update: 256 blocks x 512 thr, 1 block/CU. NT=3 (g folded into bias).
// bf16 in (ee, ve gathers = half the random-gather bytes); f32 atomics.
// LAST=true (step 1): ee is dead afterwards - skip the writeback.
// ---------------------------------------------------------------------------
template<bool LAST>
__global__ __launch_bounds__(512, 2) void edge_update_kernel(
    const int* __restrict__ senders, const int* __restrict__ receivers,
    const u32* __restrict__ veB, u32* __restrict__ eeB, float* __restrict__ agg,
    const u32* __restrict__ Wp, const float* __restrict__ F)
{
    __shared__ __align__(64) u32 SL[17664 + 1088 + 8*544];
    u32* WL = SL;
    float* WB = (float*)(SL + 17664);
    WAVE_SETUP
    float* X = (float*)(SL + 18752) + wid*544;
    const float* binSel = F + 1040 + ((blockIdx.x & 128) ? 32 : 0);
    stage_weights32(WL, WB, Wp, binSel, F, F + 1024, 17664, 16, threadIdx.x, 512);
    const int e0 = (blockIdx.x*8 + wid)*32;
    const int e  = e0 + el;
    const int b  = e >> 15;
    const int s  = senders[e], r_ = receivers[e];
    bf16x8 a[3];
    U4 c;
    c.u = *(const uint4*)(eeB + (size_t)e*8 + h*4);               a[0] = c.h;
    c.u = *(const uint4*)(veB + ((size_t)b*NN + s )*8 + h*4);     a[1] = c.h;
    c.u = *(const uint4*)(veB + ((size_t)b*NN + r_)*8 + h*4);     a[2] = c.h;
    f32x16 O = mlp32<3, true>(a, WL, WB, lane, h);
    float4 s1, s2;
    s1.x = fmaxf(O[0], 0.f); s1.y = fmaxf(O[1], 0.f);
    s1.z = fmaxf(O[2], 0.f); s1.w = fmaxf(O[3], 0.f);
    s2.x = fmaxf(O[4], 0.f); s2.y = fmaxf(O[5], 0.f);
    s2.z = fmaxf(O[6], 0.f); s2.w = fmaxf(O[7], 0.f);
    if (!LAST) {
        U4 cc;
        cc.u.x = pk2(s1.x, s1.y); cc.u.y = pk2(s1.z, s1.w);
        cc.u.z = pk2(s2.x, s2.y); cc.u.w = pk2(s2.z, s2.w);
        *(uint4*)(eeB + (size_t)e*8 + h*4) = cc.u;
    }
    // Transpose through wave-private LDS so each atomic instruction hits 4
    // receiver lines (16 lanes share a receiver). Atomics stay f32.
    *(float4*)(X + el*17 + h*4)     = s1;
    *(float4*)(X + el*17 + h*4 + 8) = s2;
    const int feat = lane & 15;
    #pragma unroll
    for (int rr = 0; rr < 8; ++rr) {
        int m = (lane >> 4)*8 + rr;
        float v = X[m*17 + feat];
        int rc = __shfl(r_, m);                // lane m (h=0) holds receivers
        int eg = e0 + m;
        atomicAdd(agg + ((size_t)(eg >> 15)*NN + rc)*16 + feat, v);
    }
}

// ---------------------------------------------------------------------------
// node_update: 256 blocks x 512 thr, 1 block/CU. NT=2 (g folded into bias).
// agg stays f32 (atomic target); ve is bf16. DEC: decode staged upfront with
// a SINGLE barrier (both DMA queues + both bias loops drain under one wait).
// ---------------------------------------------------------------------------
template<bool DEC>
__global__ __launch_bounds__(512, 2) void node_update_kernel(
    const float* __restrict__ agg, u32* __restrict__ veB,
    const u32* __restrict__ Wp, const float* __restrict__ F,
    const u32* __restrict__ Wde, const float* __restrict__ de_bin,
    const float* __restrict__ de_bh, const float* __restrict__ de_bout,
    float* __restrict__ out)
{
    __shared__ __align__(64) u32 SL[DEC ? (17408 + 17152 + 1088 + 1088) : (17408 + 1088)];
    u32* WL = SL;
    u32* WL2 = SL + 17408;
    float* WB  = (float*)(SL + (DEC ? 34560 : 17408));
    float* WB2 = (float*)(SL + 35648);
    WAVE_SETUP
    const float* binSel = F + 1040 + ((blockIdx.x & 128) ? 32 : 0);
    if (!DEC) {
        stage_weights32(WL, WB, Wp, binSel, F, F + 1024, 17408, 16,
                        threadIdx.x, 512);
    } else {
        stage_dma(WL,  Wp,  17408, threadIdx.x, 512);
        stage_dma(WL2, Wde, 17152, threadIdx.x, 512);
        stage_bias(WB,  binSel, F, F + 1024, 16, threadIdx.x, 512);
        stage_bias(WB2, de_bin, de_bh, de_bout, 3, threadIdx.x, 512);
        __syncthreads();
    }
    const int e = (blockIdx.x*8 + wid)*32 + el;
    bf16x8 a[2];
    a[0] = stage_chunk(agg, (size_t)e, h);
    {
        U4 c;
        c.u = *(const uint4*)(veB + (size_t)e*8 + h*4);
        a[1] = c.h;
    }
    f32x16 O = mlp32<2, true>(a, WL, WB, lane, h);
    if (!DEC) {
        U4 cc;
        cc.u.x = pk2(fmaxf(O[0],0.f), fmaxf(O[1],0.f));
        cc.u.y = pk2(fmaxf(O[2],0.f), fmaxf(O[3],0.f));
        cc.u.z = pk2(fmaxf(O[4],0.f), fmaxf(O[5],0.f));
        cc.u.w = pk2(fmaxf(O[6],0.f), fmaxf(O[7],0.f));
        *(uint4*)(veB + (size_t)e*8 + h*4) = cc.u;
    } else {
        bf16x8 D0, D1;
        transform32<false>(O, D0, D1);   // relu + pack
        f32x16 O2 = mlp32<1, false>(&D0, WL2, WB2, lane, h);
        if (h == 0) {
            out[(size_t)e*3 + 0] = fmaxf(O2[0], 0.f);
            out[(size_t)e*3 + 1] = fmaxf(O2[1], 0.f);
            out[(size_t)e*3 + 2] = fmaxf(O2[2], 0.f);
        }
    }
}

// ---------------------------------------------------------------------------
// launch
// ---------------------------------------------------------------------------
extern "C" void kernel_launch(void* const* d_in, const int* in_sizes, int n_in,
                              void* d_out, int out_size, void* d_ws, size_t ws_size,
                              hipStream_t stream)
{
    const float* nodes     = (const float*)d_in[0];
    const float* edges     = (const float*)d_in[1];
    const float* gvec      = (const float*)d_in[2];
    const int*   senders   = (const int*)  d_in[3];
    const int*   receivers = (const int*)  d_in[4];

    const float* ne_Win  = (const float*)d_in[5];
    const float* ne_bin  = (const float*)d_in[6];
    const float* ne_Wh   = (const float*)d_in[7];
    const float* ne_bh   = (const float*)d_in[8];
    const float* ne_Wout = (const float*)d_in[9];
    const float* ne_bout = (const float*)d_in[10];

    const float* ed_Win  = (const float*)d_in[11];
    const float* ed_bin  = (const float*)d_in[12];
    const float* ed_Wh   = (const float*)d_in[13];
    const float* ed_bh   = (const float*)d_in[14];
    const float* ed_Wout = (const float*)d_in[15];
    const float* ed_bout = (const float*)d_in[16];

    const float* pe_Win  = (const float*)d_in[17];
    const float* pe_bin  = (const float*)d_in[18];
    const float* pe_Wh   = (const float*)d_in[19];
    const float* pe_bh   = (const float*)d_in[20];
    const float* pe_Wout = (const float*)d_in[21];
    const float* pe_bout = (const float*)d_in[22];
    const float* pe_lng  = (const float*)d_in[23];
    const float* pe_lnb  = (const float*)d_in[24];

    const float* pv_Win  = (const float*)d_in[25];
    const float* pv_bin  = (const float*)d_in[26];
    const float* pv_Wh   = (const float*)d_in[27];
    const float* pv_bh   = (const float*)d_in[28];
    const float* pv_Wout = (const float*)d_in[29];
    const float* pv_bout = (const float*)d_in[30];
    const float* pv_lng  = (const float*)d_in[31];
    const float* pv_lnb  = (const float*)d_in[32];

    const float* de_Win  = (const float*)d_in[33];
    const float* de_bin  = (const float*)d_in[34];
    const float* de_Wh   = (const float*)d_in[35];
    const float* de_bh   = (const float*)d_in[36];
    const float* de_Wout = (const float*)d_in[37];
    const float* de_bout = (const float*)d_in[38];

    // workspace: veB | eeB (bf16, 4MB-spaced regions) | agg0 | agg1 (f32) |
    //            packed weights | folds
    float* ve   = (float*)d_ws;
    float* ee   = ve   + (size_t)1048576;
    float* agg0 = ee   + (size_t)1048576;
    float* agg1 = agg0 + (size_t)1048576;
    u32* veB = (u32*)ve;
    u32* eeB = (u32*)ee;
    u32* Wne = (u32*)(agg1 + (size_t)1048576);
    u32* Wed = Wne + 17152;
    u32* Wpe = Wed + 17152;
    u32* Wpv = Wpe + 17664;
    u32* Wde = Wpv + 17408;
    float* Fpe = (float*)(Wde + 17152);   // 1104 floats
    float* Fpv = Fpe + 1104;              // 1104 floats

    // prep also zeroes agg0/agg1 (blocks 349..860) - no separate memset
    prep_kernel<<<861, dim3(256), 0, stream>>>(
        ne_Win, ne_Wh, ne_Wout,
        ed_Win, ed_Wh, ed_Wout,
        pe_Win, pe_Wh, pe_Wout, pe_lng, pe_lnb, pe_bh, pe_bout, pe_bin,
        pv_Win, pv_Wh, pv_Wout, pv_lng, pv_lnb, pv_bh, pv_bout, pv_bin,
        de_Win, de_Wh, de_Wout, gvec,
        Wne, Wed, Wpe, Wpv, Wde, Fpe, Fpv, agg0);

    encode_kernel<<<512, dim3(512), 0, stream>>>(nodes, edges, gvec, senders, receivers,
        Wne, ne_bin, ne_bh, ne_bout,
        Wed, ed_bin, ed_bh, ed_bout, veB, eeB);

    // step 0
    edge_update_kernel<false><<<256, dim3(512), 0, stream>>>(senders, receivers,
        veB, eeB, agg0, Wpe, Fpe);
    node_update_kernel<false><<<256, dim3(512), 0, stream>>>(agg0, veB,
        Wpv, Fpv, Wde, de_bin, de_bh, de_bout, (float*)d_out);
    // step 1 (+ fused decode; ee store skipped - dead)
    edge_update_kernel<true><<<256, dim3(512), 0, stream>>>(senders, receivers,
        veB, eeB, agg1, Wpe, Fpe);
    node_update_kernel<true><<<256, dim3(512), 0, stream>>>(agg1, veB,
        Wpv, Fpv, Wde, de_bin, de_bh, de_bout, (float*)d_out);
}

// Round 13
// 228.910 us; speedup vs baseline: 1.0176x; 1.0163x over previous
//
#include <hip/hip_runtime.h>

#define BB 2
#define NN 32768
#define EN 32768

typedef unsigned int u32;
typedef __attribute__((ext_vector_type(8)))  short bf16x8;
typedef __attribute__((ext_vector_type(2)))  float f32x2;
typedef __attribute__((ext_vector_type(16))) float f32x16;

union U4 { uint4 u; bf16x8 h; };

// Single-instruction bf16 pack (no gfx950 builtin; RNE).
__device__ __forceinline__ u32 pk2(float lo, float hi) {
    u32 r;
    asm("v_cvt_pk_bf16_f32 %0, %1, %2" : "=v"(r) : "v"(lo), "v"(hi));
    return r;
}

// lane<->lane^32 sum via permlane32_swap (VALU, no LDS latency).
__device__ __forceinline__ float xor32_sum(float x) {
    float y = x;
    asm("v_permlane32_swap_b32 %0, %1" : "+v"(x), "+v"(y));
    return x + y;
}

__device__ __forceinline__ f32x16 MF32(bf16x8 a, bf16x8 b, f32x16 c) {
    return __builtin_amdgcn_mfma_f32_32x32x16_bf16(a, b, c, 0, 0, 0);
}

// ---------------------------------------------------------------------------
// 32x32 MFMA engine (round-10 champion, frozen). Lane (e = lane&31, h = lane>>5).
// C/D: col = e, row(r,h) = (r&3) + 8*(r>>2) + 4h.
// pi: f(t,h,j) = 16t + 4h + (j&3) + 8*(j>>2) -> layer-to-layer pure registers.
// ---------------------------------------------------------------------------
template<bool LN>
__device__ __forceinline__ void transform32(f32x16 D, bf16x8& B0, bf16x8& B1)
{
    f32x2 p0 = {D[0],D[1]},  p1 = {D[2],D[3]},  p2 = {D[4],D[5]},  p3 = {D[6],D[7]};
    f32x2 p4 = {D[8],D[9]},  p5 = {D[10],D[11]},p6 = {D[12],D[13]},p7 = {D[14],D[15]};
    const f32x2 zz = {0.f, 0.f};
    p0 = __builtin_elementwise_max(p0, zz); p1 = __builtin_elementwise_max(p1, zz);
    p2 = __builtin_elementwise_max(p2, zz); p3 = __builtin_elementwise_max(p3, zz);
    p4 = __builtin_elementwise_max(p4, zz); p5 = __builtin_elementwise_max(p5, zz);
    p6 = __builtin_elementwise_max(p6, zz); p7 = __builtin_elementwise_max(p7, zz);
    if (LN) {
        f32x2 sv = ((p0+p1)+(p2+p3)) + ((p4+p5)+(p6+p7));
        f32x2 ta = __builtin_elementwise_fma(p0,p0,
                   __builtin_elementwise_fma(p1,p1,
                   __builtin_elementwise_fma(p2,p2, p3*p3)));
        f32x2 tb = __builtin_elementwise_fma(p4,p4,
                   __builtin_elementwise_fma(p5,p5,
                   __builtin_elementwise_fma(p6,p6, p7*p7)));
        f32x2 tv = ta + tb;
        float s = xor32_sum(sv.x + sv.y);
        float t = xor32_sum(tv.x + tv.y);
        float mu  = s * (1.f/32.f);
        float var = fmaf(-mu, mu, t * (1.f/32.f));
        float rs  = rsqrtf(var + 1e-5f);
        float nt  = -mu * rs;
        f32x2 rs2 = {rs, rs}, nt2 = {nt, nt};
        p0 = __builtin_elementwise_fma(p0, rs2, nt2);
        p1 = __builtin_elementwise_fma(p1, rs2, nt2);
        p2 = __builtin_elementwise_fma(p2, rs2, nt2);
        p3 = __builtin_elementwise_fma(p3, rs2, nt2);
        p4 = __builtin_elementwise_fma(p4, rs2, nt2);
        p5 = __builtin_elementwise_fma(p5, rs2, nt2);
        p6 = __builtin_elementwise_fma(p6, rs2, nt2);
        p7 = __builtin_elementwise_fma(p7, rs2, nt2);
    }
    U4 c;
    c.u.x = pk2(p0.x,p0.y); c.u.y = pk2(p1.x,p1.y);
    c.u.z = pk2(p2.x,p2.y); c.u.w = pk2(p3.x,p3.y);
    B0 = c.h;
    c.u.x = pk2(p4.x,p4.y); c.u.y = pk2(p5.x,p5.y);
    c.u.z = pk2(p6.x,p6.y); c.u.w = pk2(p7.x,p7.y);
    B1 = c.h;
}

// Direct aligned f32x16 LDS load (WB 64B-aligned; h*16 floats = 64B).
__device__ __forceinline__ f32x16 load_biasC(const float* WB, int base, int h) {
    return *(const f32x16*)(WB + base + h*16);
}

// WL (dwords): [Bin NT*256][Bh 32*512][Bo 512]
// unroll 8 + setprio MFMA brackets; weights depth-2, bias depth-1 (proven
// optimum; depth-3/2 regressed). Prefetch clamps removed: l=30/31 over-reads
// stay inside the kernel's LDS allocation (verified per instantiation);
// junk rotates out unconsumed.
template<int NT, bool LN>
__device__ __forceinline__ f32x16 mlp32(const bf16x8* bIn,
    const u32* WL, const float* WB, int lane, int h)
{
    constexpr int HB = NT*256;
    constexpr int BO = HB + 16384;
    U4 c;
    f32x16 D = load_biasC(WB, 0, h);
    #pragma unroll
    for (int t = 0; t < NT; ++t) {
        c.u = *(const uint4*)(WL + t*256 + lane*4);
        D = MF32(c.h, bIn[t], D);
    }
    c.u = *(const uint4*)(WL + HB + lane*4);        bf16x8 w0 = c.h;
    c.u = *(const uint4*)(WL + HB + 256 + lane*4);  bf16x8 w1 = c.h;
    c.u = *(const uint4*)(WL + HB + 512 + lane*4);  bf16x8 x0 = c.h;
    c.u = *(const uint4*)(WL + HB + 768 + lane*4);  bf16x8 x1 = c.h;
    f32x16 pb = load_biasC(WB, 32, h);
    bf16x8 B0, B1;
    transform32<LN>(D, B0, B1);
    #pragma unroll 8
    for (int l = 0; l < 32; ++l) {
        c.u = *(const uint4*)(WL + HB + (l+2)*512 + lane*4);       bf16x8 nw0 = c.h;
        c.u = *(const uint4*)(WL + HB + (l+2)*512 + 256 + lane*4); bf16x8 nw1 = c.h;
        f32x16 nb = load_biasC(WB, 32 + (l+1)*32, h);
        __builtin_amdgcn_s_setprio(1);
        f32x16 E = MF32(w0, B0, pb);
        E = MF32(w1, B1, E);
        __builtin_amdgcn_s_setprio(0);
        transform32<LN>(E, B0, B1);
        w0 = x0; w1 = x1; x0 = nw0; x1 = nw1; pb = nb;
    }
    c.u = *(const uint4*)(WL + BO + lane*4);        bf16x8 o0 = c.h;
    c.u = *(const uint4*)(WL + BO + 256 + lane*4);  bf16x8 o1 = c.h;
    f32x16 Co = load_biasC(WB, 1056, h);
    __builtin_amdgcn_s_setprio(1);
    f32x16 O = MF32(o0, B0, Co);
    O = MF32(o1, B1, O);
    __builtin_amdgcn_s_setprio(0);
    return O;
}

// ---------------------------------------------------------------------------
// Staging. DMA linear; biases permuted to the C-operand layout.
// ---------------------------------------------------------------------------
__device__ __forceinline__ void stage_dma(u32* WL, const u32* __restrict__ Wp,
                                          int wtot, int tid, int nthr)
{
    const int lane = tid & 63;
    const int step = (nthr >> 6) * 256;
    for (int C = (tid >> 6)*256; C < wtot; C += step)
        __builtin_amdgcn_global_load_lds(
            (const __attribute__((address_space(1))) u32*)(Wp + C + lane*4),
            (__attribute__((address_space(3))) u32*)(WL + C), 16, 0, 0);
}

// WB (floats): [0..32) bin | [32..1056) hidden | [1056..1088) out
__device__ __forceinline__ void stage_bias(float* WB,
    const float* __restrict__ bin, const float* __restrict__ bhid,
    const float* __restrict__ bo, int nbo, int tid, int nthr)
{
    for (int i = tid; i < 1088; i += nthr) {
        float v;
        if (i < 32) {
            int w = i, hh = w>>4, r = w&15;
            int f = (r&3) + 8*(r>>2) + 4*hh;
            v = bin[f];
        } else if (i < 1056) {
            int l = (i-32)>>5, w = (i-32)&31, hh = w>>4, r = w&15;
            int f = (r&3) + 8*(r>>2) + 4*hh;
            v = bhid[l*32 + f];
        } else {
            int w = i-1056, hh = w>>4, r = w&15;
            int f = (r&3) + 8*(r>>2) + 4*hh;
            v = (f < nbo) ? bo[f] : 0.f;
        }
        WB[i] = v;
    }
}

__device__ __forceinline__ void stage_weights32(
    u32* WL, float* WB, const u32* __restrict__ Wp,
    const float* __restrict__ bin, const float* __restrict__ bhid,
    const float* __restrict__ bo, int wtot, int nbo, int tid, int nthr)
{
    stage_dma(WL, Wp, wtot, tid, nthr);
    stage_bias(WB, bin, bhid, bo, nbo, tid, nthr);
    __syncthreads();
}

// ---------------------------------------------------------------------------
// prep: weight packing to 32x32 pi layout + LN folds + per-batch g-fold bias
// + agg zeroing (replaces the separate memset dispatch).
// ---------------------------------------------------------------------------
__device__ __forceinline__ void pack_body32(
    const float* __restrict__ Win, const float* __restrict__ Wh,
    const float* __restrict__ Wout, const float* __restrict__ lng,
    u32* __restrict__ dst, int din, int dout, int NT, int lb, int tid)
{
    int t = lb * 256 + tid;
    int binW = NT * 256;
    int tot = binW + 16384 + 512;
    if (t >= tot) return;
    float lo, hi;
    if (t < binW) {
        int tt = t>>8, rem = t&255, ln_ = rem>>2, d = rem&3;
        int hh = ln_>>5, m = ln_&31;
        int f0 = 16*tt + 4*hh + 2*(d&1) + 8*(d>>1);
        lo = (f0   < din) ? Win[f0*32 + m]     : 0.f;
        hi = (f0+1 < din) ? Win[(f0+1)*32 + m] : 0.f;
    } else if (t < binW + 16384) {
        int u = t - binW, l = u>>9, v = u&511;
        int tt = v>>8, rem = v&255, ln_ = rem>>2, d = rem&3;
        int hh = ln_>>5, m = ln_&31;
        int f0 = 16*tt + 4*hh + 2*(d&1) + 8*(d>>1);
        lo = Wh[l*1024 + f0*32 + m];
        hi = Wh[l*1024 + (f0+1)*32 + m];
        if (lng) { lo *= lng[l*32 + f0]; hi *= lng[l*32 + f0 + 1]; }
    } else {
        int u = t - binW - 16384;
        int tt = u>>8, rem = u&255, ln_ = rem>>2, d = rem&3;
        int hh = ln_>>5, m = ln_&31;
        int f0 = 16*tt + 4*hh + 2*(d&1) + 8*(d>>1);
        lo = (m < dout) ? Wout[f0*dout + m]     : 0.f;
        hi = (m < dout) ? Wout[(f0+1)*dout + m] : 0.f;
        if (lng) { lo *= lng[1024 + f0]; hi *= lng[1024 + f0 + 1]; }
    }
    dst[t] = pk2(lo, hi);
}

__device__ __forceinline__ void fold_body(
    const float* __restrict__ Wh,   const float* __restrict__ bh,
    const float* __restrict__ Wout, const float* __restrict__ bout,
    const float* __restrict__ lnb,  float* __restrict__ fb, int lb, int tid)
{
    int j = lb * 256 + tid;
    if (j < 1024) {
        int l = j >> 5, jj = j & 31;
        float acc = bh[j];
        #pragma unroll
        for (int k = 0; k < 32; ++k)
            acc = fmaf(lnb[l*32 + k], Wh[l*1024 + k*32 + jj], acc);
        fb[j] = acc;
    } else if (j < 1024 + 16) {
        int jj = j - 1024;
        float acc = bout[jj];
        #pragma unroll
        for (int k = 0; k < 32; ++k)
            acc = fmaf(lnb[1024 + k], Wout[k*16 + jj], acc);
        fb[j] = acc;
    }
}

// blocks: ne 67 | ed 67 | pe 69 | pv 68 | de 67 | fold pe 5 | fold pv 5 | g 1
//         | agg-zero 512  => 861 total
__global__ __launch_bounds__(256) void prep_kernel(
    const float* ne_Win, const float* ne_Wh, const float* ne_Wout,
    const float* ed_Win, const float* ed_Wh, const float* ed_Wout,
    const float* pe_Win, const float* pe_Wh, const float* pe_Wout,
    const float* pe_lng, const float* pe_lnb, const float* pe_bh, const float* pe_bout,
    const float* pe_bin,
    const float* pv_Win, const float* pv_Wh, const float* pv_Wout,
    const float* pv_lng, const float* pv_lnb, const float* pv_bh, const float* pv_bout,
    const float* pv_bin,
    const float* de_Win, const float* de_Wh, const float* de_Wout,
    const float* gvec,
    u32* Wne, u32* Wed, u32* Wpe, u32* Wpv, u32* Wde,
    float* Fpe, float* Fpv, float* aggZ)
{
    int bx = blockIdx.x, tid = threadIdx.x;
    if      (bx < 67)  pack_body32(ne_Win, ne_Wh, ne_Wout, nullptr, Wne,  7, 16, 1, bx,       tid);
    else if (bx < 134) pack_body32(ed_Win, ed_Wh, ed_Wout, nullptr, Wed,  5, 16, 1, bx - 67,  tid);
    else if (bx < 203) pack_body32(pe_Win, pe_Wh, pe_Wout, pe_lng,  Wpe, 48, 16, 3, bx - 134, tid);
    else if (bx < 271) pack_body32(pv_Win, pv_Wh, pv_Wout, pv_lng,  Wpv, 32, 16, 2, bx - 203, tid);
    else if (bx < 338) pack_body32(de_Win, de_Wh, de_Wout, nullptr, Wde, 16,  3, 1, bx - 271, tid);
    else if (bx < 343) fold_body(pe_Wh, pe_bh, pe_Wout, pe_bout, pe_lnb, Fpe, bx - 338, tid);
    else if (bx < 348) fold_body(pv_Wh, pv_bh, pv_Wout, pv_bout, pv_lnb, Fpv, bx - 343, tid);
    else if (bx < 349) {
        // per-batch layer-0 bias with the g-feature folded in (f32, exact):
        // pe: g is feature 48; pv: g is feature 32.
        if (tid < 64) {
            int b = tid >> 5, f = tid & 31;
            Fpe[1040 + tid] = pe_bin[f] + gvec[b] * pe_Win[48*32 + f];
        } else if (tid < 128) {
            int u = tid - 64, b = u >> 5, f = u & 31;
            Fpv[1040 + u] = pv_bin[f] + gvec[b] * pv_Win[32*32 + f];
        }
    } else {
        // zero both agg ping-pong buffers (2 x 4MB f32): 512 blocks x 4KB x4
        const float4 z = {0.f, 0.f, 0.f, 0.f};
        float4* p = (float4*)aggZ + (size_t)(bx - 349)*1024;
        #pragma unroll
        for (int k = 0; k < 4; ++k)
            p[k*256 + tid] = z;
    }
}

// f32 source chunk -> B-frag (used for agg; ve/ee are stored bf16)
__device__ __forceinline__ bf16x8 stage_chunk(const float* __restrict__ arr,
                                              size_t e, int h)
{
    const int off = h*4;
    float4 a = *(const float4*)(arr + e*16 + off);
    float4 b = *(const float4*)(arr + e*16 + off + 8);
    U4 c;
    c.u.x = pk2(a.x, a.y); c.u.y = pk2(a.z, a.w);
    c.u.z = pk2(b.x, b.y); c.u.w = pk2(b.z, b.w);
    return c.h;
}

#define WAVE_SETUP \
    const int lane = threadIdx.x & 63; \
    const int wid  = threadIdx.x >> 6; \
    const int el = lane & 31, h = lane >> 5;

// ---------------------------------------------------------------------------
// encode: 512 blocks x 512 thr, 2 blocks/CU. Outputs ve/ee as bf16
// (numerically identical to f32 store + consumer pk2).
// ---------------------------------------------------------------------------
__global__ __launch_bounds__(512, 4) void encode_kernel(
    const float* __restrict__ nodes, const float* __restrict__ edges,
    const float* __restrict__ gvec,
    const int* __restrict__ senders, const int* __restrict__ receivers,
    const u32* __restrict__ Wne, const float* __restrict__ ne_bin,
    const float* __restrict__ ne_bh, const float* __restrict__ ne_bout,
    const u32* __restrict__ Wed, const float* __restrict__ ed_bin,
    const float* __restrict__ ed_bh, const float* __restrict__ ed_bout,
    u32* __restrict__ veB, u32* __restrict__ eeB)
{
    __shared__ __align__(64) u32 SL[17152 + 1088];
    u32* WL = SL;
    float* WB = (float*)(SL + 17152);
    WAVE_SETUP
    const bool edge_stage = blockIdx.x >= 256;
    stage_weights32(WL, WB,
                    edge_stage ? Wed : Wne,
                    edge_stage ? ed_bin : ne_bin,
                    edge_stage ? ed_bh : ne_bh,
                    edge_stage ? ed_bout : ne_bout,
                    17152, 16, threadIdx.x, 512);
    const int lb = edge_stage ? (blockIdx.x - 256) : blockIdx.x;
    const int e = (lb*8 + wid)*32 + el;
    const int b = e >> 15;
    bf16x8 a0;
    {
        uint4 w; w.x = 0u; w.y = 0u; w.z = 0u; w.w = 0u;
        if (!edge_stage) {
            if (h == 0) {
                float2 v01 = *(const float2*)(nodes + (size_t)e*6);
                float2 v23 = *(const float2*)(nodes + (size_t)e*6 + 2);
                w.x = pk2(v01.x, v01.y); w.y = pk2(v23.x, v23.y);
            } else {
                float2 v45 = *(const float2*)(nodes + (size_t)e*6 + 4);
                w.x = pk2(v45.x, v45.y); w.y = pk2(gvec[b], 0.f);
            }
        } else {
            int s = senders[e], r = receivers[e];
            const float* ps = nodes + ((size_t)b*NN + s)*6;
            const float* pr = nodes + ((size_t)b*NN + r)*6;
            float2 s01 = *(const float2*)ps; float s2v = ps[2];
            float2 r01 = *(const float2*)pr; float r2v = pr[2];
            float r0 = s01.x - r01.x, r1 = s01.y - r01.y, r2 = s2v - r2v;
            if (h == 0) {
                w.x = pk2(edges[e], r0); w.y = pk2(r1, r2);
            } else {
                w.x = pk2(sqrtf(r0*r0 + r1*r1 + r2*r2), 0.f);
            }
        }
        U4 c; c.u = w; a0 = c.h;
    }
    u32* dstB = edge_stage ? eeB : veB;
    f32x16 O = mlp32<1, false>(&a0, WL, WB, lane, h);
    U4 cc;
    cc.u.x = pk2(fmaxf(O[0],0.f), fmaxf(O[1],0.f));
    cc.u.y = pk2(fmaxf(O[2],0.f), fmaxf(O[3],0.f));
    cc.u.z = pk2(fmaxf(O[4],0.f), fmaxf(O[5],0.f));
    cc.u.w = pk2(fmaxf(O[6],0.f), fmaxf(O[7],0.f));
    *(uint4*)(dstB + (size_t)e*8 + h*4) = cc.u;
}

// ---------------------------------------------------------------------------
// edge_update: 256 blocks x 512 thr, 1 block/CU. NT=3 (g folded into bias).
// bf16 in (ee, ve gathers = half the random-gather bytes), bf16 out (ee);
// f32 atomics for agg.
// ---------------------------------------------------------------------------
__global__ __launch_bounds__(512, 2) void edge_update_kernel(
    const int* __restrict__ senders, const int* __restrict__ receivers,
    const u32* __restrict__ veB, u32* __restrict__ eeB, float* __restrict__ agg,
    const u32* __restrict__ Wp, const float* __restrict__ F)
{
    __shared__ __align__(64) u32 SL[17664 + 1088 + 8*544];
    u32* WL = SL;
    float* WB = (float*)(SL + 17664);
    WAVE_SETUP
    float* X = (float*)(SL + 18752) + wid*544;
    const float* binSel = F + 1040 + ((blockIdx.x & 128) ? 32 : 0);
    stage_weights32(WL, WB, Wp, binSel, F, F + 1024, 17664, 16, threadIdx.x, 512);
    const int e0 = (blockIdx.x*8 + wid)*32;
    const int e  = e0 + el;
    const int b  = e >> 15;
    const int s  = senders[e], r_ = receivers[e];
    bf16x8 a[3];
    U4 c;
    c.u = *(const uint4*)(eeB + (size_t)e*8 + h*4);               a[0] = c.h;
    c.u = *(const uint4*)(veB + ((size_t)b*NN + s )*8 + h*4);     a[1] = c.h;
    c.u = *(const uint4*)(veB + ((size_t)b*NN + r_)*8 + h*4);     a[2] = c.h;
    f32x16 O = mlp32<3, true>(a, WL, WB, lane, h);
    float4 s1, s2;
    s1.x = fmaxf(O[0], 0.f); s1.y = fmaxf(O[1], 0.f);
    s1.z = fmaxf(O[2], 0.f); s1.w = fmaxf(O[3], 0.f);
    s2.x = fmaxf(O[4], 0.f); s2.y = fmaxf(O[5], 0.f);
    s2.z = fmaxf(O[6], 0.f); s2.w = fmaxf(O[7], 0.f);
    U4 cc;
    cc.u.x = pk2(s1.x, s1.y); cc.u.y = pk2(s1.z, s1.w);
    cc.u.z = pk2(s2.x, s2.y); cc.u.w = pk2(s2.z, s2.w);
    *(uint4*)(eeB + (size_t)e*8 + h*4) = cc.u;
    // Transpose through wave-private LDS so each atomic instruction hits 4
    // receiver lines (16 lanes share a receiver). Atomics stay f32.
    *(float4*)(X + el*17 + h*4)     = s1;
    *(float4*)(X + el*17 + h*4 + 8) = s2;
    const int feat = lane & 15;
    #pragma unroll
    for (int rr = 0; rr < 8; ++rr) {
        int m = (lane >> 4)*8 + rr;
        float v = X[m*17 + feat];
        int rc = __shfl(r_, m);                // lane m (h=0) holds receivers
        int eg = e0 + m;
        atomicAdd(agg + ((size_t)(eg >> 15)*NN + rc)*16 + feat, v);
    }
}

// ---------------------------------------------------------------------------
// node_update: 256 blocks x 512 thr, 1 block/CU. NT=2 (g folded into bias).
// agg stays f32 (atomic target); ve is bf16. DEC: decode staged upfront.
// ---------------------------------------------------------------------------
template<bool DEC>
__global__ __launch_bounds__(512, 2) void node_update_kernel(
    const float* __restrict__ agg, u32* __restrict__ veB,
    const u32* __restrict__ Wp, const float* __restrict__ F,
    const u32* __restrict__ Wde, const float* __restrict__ de_bin,
    const float* __restrict__ de_bh, const float* __restrict__ de_bout,
    float* __restrict__ out)
{
    __shared__ __align__(64) u32 SL[DEC ? (17408 + 17152 + 1088 + 1088) : (17408 + 1088)];
    u32* WL = SL;
    u32* WL2 = SL + 17408;
    float* WB  = (float*)(SL + (DEC ? 34560 : 17408));
    float* WB2 = (float*)(SL + 35648);
    WAVE_SETUP
    const float* binSel = F + 1040 + ((blockIdx.x & 128) ? 32 : 0);
    stage_weights32(WL, WB, Wp, binSel, F, F + 1024, 17408, 16, threadIdx.x, 512);
    if (DEC)
        stage_weights32(WL2, WB2, Wde, de_bin, de_bh, de_bout, 17152, 3,
                        threadIdx.x, 512);
    const int e = (blockIdx.x*8 + wid)*32 + el;
    bf16x8 a[2];
    a[0] = stage_chunk(agg, (size_t)e, h);
    {
        U4 c;
        c.u = *(const uint4*)(veB + (size_t)e*8 + h*4);
        a[1] = c.h;
    }
    f32x16 O = mlp32<2, true>(a, WL, WB, lane, h);
    if (!DEC) {
        U4 cc;
        cc.u.x = pk2(fmaxf(O[0],0.f), fmaxf(O[1],0.f));
        cc.u.y = pk2(fmaxf(O[2],0.f), fmaxf(O[3],0.f));
        cc.u.z = pk2(fmaxf(O[4],0.f), fmaxf(O[5],0.f));
        cc.u.w = pk2(fmaxf(O[6],0.f), fmaxf(O[7],0.f));
        *(uint4*)(veB + (size_t)e*8 + h*4) = cc.u;
    } else {
        bf16x8 D0, D1;
        transform32<false>(O, D0, D1);   // relu + pack
        f32x16 O2 = mlp32<1, false>(&D0, WL2, WB2, lane, h);
        if (h == 0) {
            out[(size_t)e*3 + 0] = fmaxf(O2[0], 0.f);
            out[(size_t)e*3 + 1] = fmaxf(O2[1], 0.f);
            out[(size_t)e*3 + 2] = fmaxf(O2[2], 0.f);
        }
    }
}

// ---------------------------------------------------------------------------
// launch
// ---------------------------------------------------------------------------
extern "C" void kernel_launch(void* const* d_in, const int* in_sizes, int n_in,
                              void* d_out, int out_size, void* d_ws, size_t ws_size,
                              hipStream_t stream)
{
    const float* nodes     = (const float*)d_in[0];
    const float* edges     = (const float*)d_in[1];
    const float* gvec      = (const float*)d_in[2];
    const int*   senders   = (const int*)  d_in[3];
    const int*   receivers = (const int*)  d_in[4];

    const float* ne_Win  = (const float*)d_in[5];
    const float* ne_bin  = (const float*)d_in[6];
    const float* ne_Wh   = (const float*)d_in[7];
    const float* ne_bh   = (const float*)d_in[8];
    const float* ne_Wout = (const float*)d_in[9];
    const float* ne_bout = (const float*)d_in[10];

    const float* ed_Win  = (const float*)d_in[11];
    const float* ed_bin  = (const float*)d_in[12];
    const float* ed_Wh   = (const float*)d_in[13];
    const float* ed_bh   = (const float*)d_in[14];
    const float* ed_Wout = (const float*)d_in[15];
    const float* ed_bout = (const float*)d_in[16];

    const float* pe_Win  = (const float*)d_in[17];
    const float* pe_bin  = (const float*)d_in[18];
    const float* pe_Wh   = (const float*)d_in[19];
    const float* pe_bh   = (const float*)d_in[20];
    const float* pe_Wout = (const float*)d_in[21];
    const float* pe_bout = (const float*)d_in[22];
    const float* pe_lng  = (const float*)d_in[23];
    const float* pe_lnb  = (const float*)d_in[24];

    const float* pv_Win  = (const float*)d_in[25];
    const float* pv_bin  = (const float*)d_in[26];
    const float* pv_Wh   = (const float*)d_in[27];
    const float* pv_bh   = (const float*)d_in[28];
    const float* pv_Wout = (const float*)d_in[29];
    const float* pv_bout = (const float*)d_in[30];
    const float* pv_lng  = (const float*)d_in[31];
    const float* pv_lnb  = (const float*)d_in[32];

    const float* de_Win  = (const float*)d_in[33];
    const float* de_bin  = (const float*)d_in[34];
    const float* de_Wh   = (const float*)d_in[35];
    const float* de_bh   = (const float*)d_in[36];
    const float* de_Wout = (const float*)d_in[37];
    const float* de_bout = (const float*)d_in[38];

    // workspace: veB | eeB (bf16, 4MB-spaced regions) | agg0 | agg1 (f32) |
    //            packed weights | folds
    float* ve   = (float*)d_ws;
    float* ee   = ve   + (size_t)1048576;
    float* agg0 = ee   + (size_t)1048576;
    float* agg1 = agg0 + (size_t)1048576;
    u32* veB = (u32*)ve;
    u32* eeB = (u32*)ee;
    u32* Wne = (u32*)(agg1 + (size_t)1048576);
    u32* Wed = Wne + 17152;
    u32* Wpe = Wed + 17152;
    u32* Wpv = Wpe + 17664;
    u32* Wde = Wpv + 17408;
    float* Fpe = (float*)(Wde + 17152);   // 1104 floats
    float* Fpv = Fpe + 1104;              // 1104 floats

    // prep also zeroes agg0/agg1 (blocks 349..860) - no separate memset
    prep_kernel<<<861, dim3(256), 0, stream>>>(
        ne_Win, ne_Wh, ne_Wout,
        ed_Win, ed_Wh, ed_Wout,
        pe_Win, pe_Wh, pe_Wout, pe_lng, pe_lnb, pe_bh, pe_bout, pe_bin,
        pv_Win, pv_Wh, pv_Wout, pv_lng, pv_lnb, pv_bh, pv_bout, pv_bin,
        de_Win, de_Wh, de_Wout, gvec,
        Wne, Wed, Wpe, Wpv, Wde, Fpe, Fpv, agg0);

    encode_kernel<<<512, dim3(512), 0, stream>>>(nodes, edges, gvec, senders, receivers,
        Wne, ne_bin, ne_bh, ne_bout,
        Wed, ed_bin, ed_bh, ed_bout, veB, eeB);

    // step 0
    edge_update_kernel<<<256, dim3(512), 0, stream>>>(senders, receivers,
        veB, eeB, agg0, Wpe, Fpe);
    node_update_kernel<false><<<256, dim3(512), 0, stream>>>(agg0, veB,
        Wpv, Fpv, Wde, de_bin, de_bh, de_bout, (float*)d_out);
    // step 1 (+ fused decode)
    edge_update_kernel<<<256, dim3(512), 0, stream>>>(senders, receivers,
        veB, eeB, agg1, Wpe, Fpe);
    node_update_kernel<true><<<256, dim3(512), 0, stream>>>(agg1, veB,
        Wpv, Fpv, Wde, de_bin, de_bh, de_bout, (float*)d_out);
}